// Round 5
// baseline (461.124 us; speedup 1.0000x reference)
//
#include <hip/hip_runtime.h>
#include <math.h>

#define NLV 16
#define TBL (1u << 19)
#define HMASK (TBL - 1u)
#define PRIME1 2654435761u

struct Scales { float s[NLV]; };

// L2-request-rate theory: 64 divergent gathers/pt = 67M line requests ~= 218us
// at ~128 req/cycle chip-wide. Reduce requests via the x-pair identity:
// even bx -> (bx+1)^h == (bx^h)^1, so both x-corners sit in one aligned
// 16B pair -> one float4 load. Odd-bx lanes fetch 2 extras under exec mask.
// 4 -> 3 avg lane-requests per level (-25% total). No LDS, no big arrays,
// no sched fences: round-4 failed on scratch spills (WRITE_SIZE 544 MB).
__global__ __launch_bounds__(256, 4) void hashgrid_mlp_kernel(
    const float2* __restrict__ pts,
    const float2* __restrict__ table,   // [16][524288] float2
    const float*  __restrict__ W1,      // [64][32]
    const float*  __restrict__ W2,      // [3][64]
    float* __restrict__ out,            // [N][3]
    int N, Scales sc)
{
    int i = blockIdx.x * 256 + threadIdx.x;
    if (i >= N) return;

    float2 p = pts[i];
    float enc[32];

#pragma unroll
    for (int l = 0; l < NLV; ++l) {
        float s  = sc.s[l];
        float px = p.x * s;              // f32 mul, bitwise == reference
        float py = p.y * s;
        float fpx = floorf(px), fpy = floorf(py);
        float fx = px - fpx, fy = py - fpy;
        unsigned bx = (unsigned)(int)fpx;
        unsigned by = (unsigned)(int)fpy;
        unsigned hy0 = by * PRIME1;
        unsigned hy1 = hy0 + PRIME1;     // (by+1)*PRIME1 mod 2^32
        unsigned i0 = (bx ^ hy0) & HMASK;
        unsigned i1 = (bx ^ hy1) & HMASK;
        const float2* tl = table + (size_t)l * TBL;

        // one 16B load covers entries {i&~1, i|1} (always in-bounds: mask
        // spans full pow2 range, 16B-aligned since table base is)
        float4 q0 = *(const float4*)(tl + (i0 & ~1u));
        float4 q1 = *(const float4*)(tl + (i1 & ~1u));

        float2 f00 = (i0 & 1u) ? make_float2(q0.z, q0.w) : make_float2(q0.x, q0.y);
        float2 f01 = (i1 & 1u) ? make_float2(q1.z, q1.w) : make_float2(q1.x, q1.y);

        float2 f10, f11;
        if (bx & 1u) {
            // odd bx: x+1 flips multiple bits -> unrelated entry, exec-masked loads
            f10 = tl[((bx + 1u) ^ hy0) & HMASK];
            f11 = tl[((bx + 1u) ^ hy1) & HMASK];
        } else {
            // even bx: x-corner pair is the other half of the same 16B pair
            f10 = (i0 & 1u) ? make_float2(q0.x, q0.y) : make_float2(q0.z, q0.w);
            f11 = (i1 & 1u) ? make_float2(q1.x, q1.y) : make_float2(q1.z, q1.w);
        }

        float gx = 1.f - fx, gy = 1.f - fy;
        float w00 = gx * gy, w01 = gx * fy, w10 = fx * gy, w11 = fx * fy;
        enc[2*l]   = w00*f00.x + w01*f01.x + w10*f10.x + w11*f11.x;
        enc[2*l+1] = w00*f00.y + w01*f01.y + w10*f10.y + w11*f11.y;
    }

    // ---- MLP 32 -> 64 (ReLU) -> 3 ----
    float o0 = 0.f, o1 = 0.f, o2 = 0.f;
#pragma unroll
    for (int j = 0; j < 64; ++j) {
        float h = 0.f;
#pragma unroll
        for (int k = 0; k < 32; ++k)
            h = fmaf(enc[k], W1[j*32 + k], h);   // uniform addr -> s_load
        h = fmaxf(h, 0.f);
        o0 = fmaf(h, W2[      j], o0);
        o1 = fmaf(h, W2[ 64 + j], o1);
        o2 = fmaf(h, W2[128 + j], o2);
    }
    out[3*i + 0] = o0;
    out[3*i + 1] = o1;
    out[3*i + 2] = o2;
}

extern "C" void kernel_launch(void* const* d_in, const int* in_sizes, int n_in,
                              void* d_out, int out_size, void* d_ws, size_t ws_size,
                              hipStream_t stream) {
    const float2* pts   = (const float2*)d_in[0];
    const float2* table = (const float2*)d_in[1];
    const float*  W1    = (const float*)d_in[2];
    const float*  W2    = (const float*)d_in[3];
    float* out = (float*)d_out;
    int N = in_sizes[0] / 2;

    // Replicate numpy: np.floor(16 * 1.447269237440378 ** arange(16)).astype(f32)
    // Host pow == glibc pow == numpy's npy_pow -> bit-identical scales
    // (level 15 is a floor boundary: 4095, NOT 4096).
    Scales sc;
    for (int l = 0; l < NLV; ++l)
        sc.s[l] = (float)floor(16.0 * pow(1.447269237440378, (double)l));

    int blocks = (N + 255) / 256;
    hipLaunchKernelGGL(hashgrid_mlp_kernel, dim3(blocks), dim3(256), 0, stream,
                       pts, table, W1, W2, out, N, sc);
}

// Round 6
// 304.795 us; speedup vs baseline: 1.5129x; 1.5129x over previous
//
#include <hip/hip_runtime.h>
#include <math.h>

#define NLV 16
#define TBL (1u << 19)
#define HMASK (TBL - 1u)
#define PRIME1 2654435761u

#define NCOARSE 5           // levels 0..4 served from LDS dense tables
#define DENSE_TOTAL 9466    // padded: each level starts at an even entry index

struct Scales { float s[NLV]; };

// widths (scale_l + 1) and padded offsets for levels 0..4
__device__ __constant__ const int DW[NCOARSE]       = {17, 24, 34, 49, 71};
__device__ __constant__ const int DOFF[NCOARSE + 1] = {0, 290, 866, 2022, 4424, 9466};

// ---- pre-kernel: densify coarse levels (hash -> [y][x]) into ws ----
__global__ void build_dense_kernel(const float2* __restrict__ table,
                                   float2* __restrict__ dense) {
    int t = blockIdx.x * 256 + threadIdx.x;
    if (t >= DENSE_TOTAL) return;
    int l = 0;
#pragma unroll
    for (int k = 1; k < NCOARSE; ++k)
        if (t >= DOFF[k]) l = k;
    int r = t - DOFF[l];
    int w = DW[l];
    if (r >= w * w) { dense[t] = make_float2(0.f, 0.f); return; }  // pad slot
    unsigned x = (unsigned)(r % w);
    unsigned y = (unsigned)(r / w);
    unsigned idx = (x ^ (y * PRIME1)) & HMASK;
    dense[t] = table[(size_t)l * TBL + idx];
}

// ---- main kernel: round-1 structure + LDS coarse levels ----
// Levels 0-4 (20 of 64 gathers) served from a 75.7 KB LDS dense table
// (2 blocks/CU). Levels 5-15 stay as plain float2 gathers — round-1
// codegen, which is the only variant that didn't spill (WRITE ~12 MB).
// Theory: L2 is request-rate bound (~14 req/cyc/XCD of ~16); removing
// 27% of lane-requests should cut time proportionally.
__global__ __launch_bounds__(256, 2) void hashgrid_mlp_kernel(
    const float2* __restrict__ pts,
    const float2* __restrict__ table,   // [16][524288] float2
    const float2* __restrict__ dense,   // ws dense coarse tables (padded)
    const float*  __restrict__ W1,      // [64][32]
    const float*  __restrict__ W2,      // [3][64]
    float* __restrict__ out,            // [N][3]
    int N, Scales sc)
{
    __shared__ float2 sd[DENSE_TOTAL];  // 75,728 B
    {
        float4* s4 = (float4*)sd;
        const float4* g4 = (const float4*)dense;
        for (int k = threadIdx.x; k < DENSE_TOTAL / 2; k += 256)
            s4[k] = g4[k];
    }
    __syncthreads();

    int i = blockIdx.x * 256 + threadIdx.x;
    if (i >= N) return;

    float2 p = pts[i];
    float enc[32];

    // ---- coarse levels from LDS ----
#pragma unroll
    for (int l = 0; l < NCOARSE; ++l) {
        float s  = sc.s[l];
        float px = p.x * s;              // f32 mul, bitwise == reference
        float py = p.y * s;
        float fpx = floorf(px), fpy = floorf(py);
        float fx = px - fpx, fy = py - fpy;
        int bx = (int)fpx, by = (int)fpy;
        int li = DOFF[l] + by * DW[l] + bx;
        float2 f00 = sd[li];
        float2 f01 = sd[li + DW[l]];
        float2 f10 = sd[li + 1];
        float2 f11 = sd[li + DW[l] + 1];
        float gx = 1.f - fx, gy = 1.f - fy;
        float w00 = gx * gy, w01 = gx * fy, w10 = fx * gy, w11 = fx * fy;
        enc[2*l]   = w00*f00.x + w01*f01.x + w10*f10.x + w11*f11.x;
        enc[2*l+1] = w00*f00.y + w01*f01.y + w10*f10.y + w11*f11.y;
    }

    // ---- fine levels 5..15: plain gathers (known-good codegen) ----
#pragma unroll
    for (int l = NCOARSE; l < NLV; ++l) {
        float s  = sc.s[l];
        float px = p.x * s;
        float py = p.y * s;
        float fpx = floorf(px), fpy = floorf(py);
        float fx = px - fpx, fy = py - fpy;
        unsigned bx = (unsigned)(int)fpx;
        unsigned by = (unsigned)(int)fpy;
        unsigned hy0 = by * PRIME1;
        unsigned hy1 = hy0 + PRIME1;     // (by+1)*PRIME1 mod 2^32
        const float2* tl = table + (size_t)l * TBL;
        float2 f00 = tl[( bx        ^ hy0) & HMASK];
        float2 f01 = tl[( bx        ^ hy1) & HMASK];
        float2 f10 = tl[((bx + 1u)  ^ hy0) & HMASK];
        float2 f11 = tl[((bx + 1u)  ^ hy1) & HMASK];
        float gx = 1.f - fx, gy = 1.f - fy;
        float w00 = gx * gy, w01 = gx * fy, w10 = fx * gy, w11 = fx * fy;
        enc[2*l]   = w00*f00.x + w01*f01.x + w10*f10.x + w11*f11.x;
        enc[2*l+1] = w00*f00.y + w01*f01.y + w10*f10.y + w11*f11.y;
    }

    // ---- MLP 32 -> 64 (ReLU) -> 3 ----
    float o0 = 0.f, o1 = 0.f, o2 = 0.f;
#pragma unroll
    for (int j = 0; j < 64; ++j) {
        float h = 0.f;
#pragma unroll
        for (int k = 0; k < 32; ++k)
            h = fmaf(enc[k], W1[j*32 + k], h);   // uniform addr -> s_load
        h = fmaxf(h, 0.f);
        o0 = fmaf(h, W2[      j], o0);
        o1 = fmaf(h, W2[ 64 + j], o1);
        o2 = fmaf(h, W2[128 + j], o2);
    }
    out[3*i + 0] = o0;
    out[3*i + 1] = o1;
    out[3*i + 2] = o2;
}

// ---- fallback (round-1) if ws too small ----
__global__ __launch_bounds__(256, 4) void hashgrid_mlp_fallback(
    const float2* __restrict__ pts, const float2* __restrict__ table,
    const float* __restrict__ W1, const float* __restrict__ W2,
    float* __restrict__ out, int N, Scales sc)
{
    int i = blockIdx.x * 256 + threadIdx.x;
    if (i >= N) return;
    float2 p = pts[i];
    float enc[32];
#pragma unroll
    for (int l = 0; l < NLV; ++l) {
        float s = sc.s[l];
        float px = p.x * s, py = p.y * s;
        float fpx = floorf(px), fpy = floorf(py);
        float fx = px - fpx, fy = py - fpy;
        unsigned bx = (unsigned)(int)fpx, by = (unsigned)(int)fpy;
        unsigned hy0 = by * PRIME1, hy1 = hy0 + PRIME1;
        const float2* tl = table + (size_t)l * TBL;
        float2 f00 = tl[( bx       ^ hy0) & HMASK];
        float2 f01 = tl[( bx       ^ hy1) & HMASK];
        float2 f10 = tl[((bx + 1u) ^ hy0) & HMASK];
        float2 f11 = tl[((bx + 1u) ^ hy1) & HMASK];
        float gx = 1.f - fx, gy = 1.f - fy;
        float w00 = gx * gy, w01 = gx * fy, w10 = fx * gy, w11 = fx * fy;
        enc[2*l]   = w00*f00.x + w01*f01.x + w10*f10.x + w11*f11.x;
        enc[2*l+1] = w00*f00.y + w01*f01.y + w10*f10.y + w11*f11.y;
    }
    float o0 = 0.f, o1 = 0.f, o2 = 0.f;
#pragma unroll
    for (int j = 0; j < 64; ++j) {
        float h = 0.f;
#pragma unroll
        for (int k = 0; k < 32; ++k) h = fmaf(enc[k], W1[j*32 + k], h);
        h = fmaxf(h, 0.f);
        o0 = fmaf(h, W2[j], o0); o1 = fmaf(h, W2[64 + j], o1); o2 = fmaf(h, W2[128 + j], o2);
    }
    out[3*i] = o0; out[3*i + 1] = o1; out[3*i + 2] = o2;
}

extern "C" void kernel_launch(void* const* d_in, const int* in_sizes, int n_in,
                              void* d_out, int out_size, void* d_ws, size_t ws_size,
                              hipStream_t stream) {
    const float2* pts   = (const float2*)d_in[0];
    const float2* table = (const float2*)d_in[1];
    const float*  W1    = (const float*)d_in[2];
    const float*  W2    = (const float*)d_in[3];
    float* out = (float*)d_out;
    int N = in_sizes[0] / 2;

    // Replicate numpy: np.floor(16 * 1.447269237440378 ** arange(16)).astype(f32)
    // Host pow == glibc pow == numpy's npy_pow -> bit-identical scales
    // (level 15 is a floor boundary: 4095, NOT 4096).
    Scales sc;
    for (int l = 0; l < NLV; ++l)
        sc.s[l] = (float)floor(16.0 * pow(1.447269237440378, (double)l));

    if (ws_size >= DENSE_TOTAL * sizeof(float2)) {
        float2* dense = (float2*)d_ws;
        hipLaunchKernelGGL(build_dense_kernel, dim3((DENSE_TOTAL + 255) / 256),
                           dim3(256), 0, stream, table, dense);
        int blocks = (N + 255) / 256;
        hipLaunchKernelGGL(hashgrid_mlp_kernel, dim3(blocks), dim3(256), 0, stream,
                           pts, table, dense, W1, W2, out, N, sc);
    } else {
        int blocks = (N + 255) / 256;
        hipLaunchKernelGGL(hashgrid_mlp_fallback, dim3(blocks), dim3(256), 0, stream,
                           pts, table, W1, W2, out, N, sc);
    }
}

// Round 7
// 216.730 us; speedup vs baseline: 2.1276x; 1.4063x over previous
//
#include <hip/hip_runtime.h>
#include <math.h>

#define NLV 16
#define TBL (1u << 19)
#define HMASK (TBL - 1u)
#define PRIME1 2654435761u

#define BINSHIFT 7                   // 128 x 128 spatial bins
#define BINW (1 << BINSHIFT)
#define NBINS (BINW * BINW)

struct Scales { float s[NLV]; };

__device__ __forceinline__ int point_bin(float2 p) {
    // p in [0,1): (int)(x*128) in [0,127] exactly (f32 < 1.0 stays < 128.0)
    int bx = (int)(p.x * (float)BINW);
    int by = (int)(p.y * (float)BINW);
    return (by << BINSHIFT) + bx;
}

// ---- pass 1: per-bin histogram ----
__global__ void hist_kernel(const float2* __restrict__ pts, int* __restrict__ hist, int N) {
    int i = blockIdx.x * 256 + threadIdx.x;
    if (i >= N) return;
    atomicAdd(&hist[point_bin(pts[i])], 1);
}

// ---- pass 2: in-place exclusive scan of NBINS counters (1 block) ----
__global__ __launch_bounds__(1024) void scan_kernel(int* __restrict__ hist) {
    __shared__ int partials[1024];
    int tid = threadIdx.x;
    int v[NBINS / 1024];
    int sum = 0;
#pragma unroll
    for (int k = 0; k < NBINS / 1024; ++k) {
        v[k] = hist[tid * (NBINS / 1024) + k];
        sum += v[k];
    }
    partials[tid] = sum;
    __syncthreads();
    for (int off = 1; off < 1024; off <<= 1) {
        int t = (tid >= off) ? partials[tid - off] : 0;
        __syncthreads();
        partials[tid] += t;
        __syncthreads();
    }
    int run = partials[tid] - sum;   // exclusive base for this thread's chunk
#pragma unroll
    for (int k = 0; k < NBINS / 1024; ++k) {
        hist[tid * (NBINS / 1024) + k] = run;
        run += v[k];
    }
}

// ---- pass 3: scatter point indices into bin-sorted order ----
__global__ void scatter_kernel(const float2* __restrict__ pts, int* __restrict__ cur,
                               int* __restrict__ sidx, int N) {
    int i = blockIdx.x * 256 + threadIdx.x;
    if (i >= N) return;
    int pos = atomicAdd(&cur[point_bin(pts[i])], 1);
    sidx[pos] = i;
}

// ---- main kernel: round-1 structure (known-good codegen) + sorted order ----
// A wave's 64 points are now spatially adjacent: coarse/mid-level gathers
// coalesce to 1-2 lines per instruction (TCP merges same-line lanes), and
// fine-level table lines are filled into L2 once per region, not once per
// point. Attacks both the fill path (744 MB @ ~2.9 TB/s) and request rate.
__global__ __launch_bounds__(256, 4) void hashgrid_mlp_kernel(
    const float2* __restrict__ pts,
    const float2* __restrict__ table,   // [16][524288] float2
    const int*    __restrict__ sidx,    // bin-sorted point indices
    const float*  __restrict__ W1,      // [64][32]
    const float*  __restrict__ W2,      // [3][64]
    float* __restrict__ out,            // [N][3]
    int N, Scales sc)
{
    int j = blockIdx.x * 256 + threadIdx.x;
    if (j >= N) return;
    int i = sidx[j];

    float2 p = pts[i];
    float enc[32];

#pragma unroll
    for (int l = 0; l < NLV; ++l) {
        float s  = sc.s[l];
        float px = p.x * s;              // f32 mul, bitwise == reference
        float py = p.y * s;
        float fpx = floorf(px), fpy = floorf(py);
        float fx = px - fpx, fy = py - fpy;
        unsigned bx = (unsigned)(int)fpx;
        unsigned by = (unsigned)(int)fpy;
        unsigned hy0 = by * PRIME1;
        unsigned hy1 = hy0 + PRIME1;     // (by+1)*PRIME1 mod 2^32
        const float2* tl = table + (size_t)l * TBL;
        float2 f00 = tl[( bx        ^ hy0) & HMASK];
        float2 f01 = tl[( bx        ^ hy1) & HMASK];
        float2 f10 = tl[((bx + 1u)  ^ hy0) & HMASK];
        float2 f11 = tl[((bx + 1u)  ^ hy1) & HMASK];
        float gx = 1.f - fx, gy = 1.f - fy;
        float w00 = gx * gy, w01 = gx * fy, w10 = fx * gy, w11 = fx * fy;
        enc[2*l]   = w00*f00.x + w01*f01.x + w10*f10.x + w11*f11.x;
        enc[2*l+1] = w00*f00.y + w01*f01.y + w10*f10.y + w11*f11.y;
    }

    float o0 = 0.f, o1 = 0.f, o2 = 0.f;
#pragma unroll
    for (int j2 = 0; j2 < 64; ++j2) {
        float h = 0.f;
#pragma unroll
        for (int k = 0; k < 32; ++k)
            h = fmaf(enc[k], W1[j2*32 + k], h);  // uniform addr -> s_load
        h = fmaxf(h, 0.f);
        o0 = fmaf(h, W2[       j2], o0);
        o1 = fmaf(h, W2[ 64 +  j2], o1);
        o2 = fmaf(h, W2[128 +  j2], o2);
    }
    out[3*i + 0] = o0;
    out[3*i + 1] = o1;
    out[3*i + 2] = o2;
}

// ---- fallback (round-1) if ws too small for the sort ----
__global__ __launch_bounds__(256, 4) void hashgrid_mlp_fallback(
    const float2* __restrict__ pts, const float2* __restrict__ table,
    const float* __restrict__ W1, const float* __restrict__ W2,
    float* __restrict__ out, int N, Scales sc)
{
    int i = blockIdx.x * 256 + threadIdx.x;
    if (i >= N) return;
    float2 p = pts[i];
    float enc[32];
#pragma unroll
    for (int l = 0; l < NLV; ++l) {
        float s = sc.s[l];
        float px = p.x * s, py = p.y * s;
        float fpx = floorf(px), fpy = floorf(py);
        float fx = px - fpx, fy = py - fpy;
        unsigned bx = (unsigned)(int)fpx, by = (unsigned)(int)fpy;
        unsigned hy0 = by * PRIME1, hy1 = hy0 + PRIME1;
        const float2* tl = table + (size_t)l * TBL;
        float2 f00 = tl[( bx       ^ hy0) & HMASK];
        float2 f01 = tl[( bx       ^ hy1) & HMASK];
        float2 f10 = tl[((bx + 1u) ^ hy0) & HMASK];
        float2 f11 = tl[((bx + 1u) ^ hy1) & HMASK];
        float gx = 1.f - fx, gy = 1.f - fy;
        float w00 = gx * gy, w01 = gx * fy, w10 = fx * gy, w11 = fx * fy;
        enc[2*l]   = w00*f00.x + w01*f01.x + w10*f10.x + w11*f11.x;
        enc[2*l+1] = w00*f00.y + w01*f01.y + w10*f10.y + w11*f11.y;
    }
    float o0 = 0.f, o1 = 0.f, o2 = 0.f;
#pragma unroll
    for (int j = 0; j < 64; ++j) {
        float h = 0.f;
#pragma unroll
        for (int k = 0; k < 32; ++k) h = fmaf(enc[k], W1[j*32 + k], h);
        h = fmaxf(h, 0.f);
        o0 = fmaf(h, W2[j], o0); o1 = fmaf(h, W2[64 + j], o1); o2 = fmaf(h, W2[128 + j], o2);
    }
    out[3*i] = o0; out[3*i + 1] = o1; out[3*i + 2] = o2;
}

extern "C" void kernel_launch(void* const* d_in, const int* in_sizes, int n_in,
                              void* d_out, int out_size, void* d_ws, size_t ws_size,
                              hipStream_t stream) {
    const float2* pts   = (const float2*)d_in[0];
    const float2* table = (const float2*)d_in[1];
    const float*  W1    = (const float*)d_in[2];
    const float*  W2    = (const float*)d_in[3];
    float* out = (float*)d_out;
    int N = in_sizes[0] / 2;

    // Replicate numpy: np.floor(16 * 1.447269237440378 ** arange(16)).astype(f32)
    // Host pow == glibc pow == numpy's npy_pow -> bit-identical scales
    // (level 15 is a floor boundary: 4095, NOT 4096).
    Scales sc;
    for (int l = 0; l < NLV; ++l)
        sc.s[l] = (float)floor(16.0 * pow(1.447269237440378, (double)l));

    size_t need = (size_t)(NBINS + N) * sizeof(int);
    int blocks = (N + 255) / 256;
    if (ws_size >= need) {
        int* hist = (int*)d_ws;          // NBINS counters, reused as cursors
        int* sidx = hist + NBINS;        // N sorted indices
        hipMemsetAsync(hist, 0, NBINS * sizeof(int), stream);
        hipLaunchKernelGGL(hist_kernel,    dim3(blocks), dim3(256),  0, stream, pts, hist, N);
        hipLaunchKernelGGL(scan_kernel,    dim3(1),      dim3(1024), 0, stream, hist);
        hipLaunchKernelGGL(scatter_kernel, dim3(blocks), dim3(256),  0, stream, pts, hist, sidx, N);
        hipLaunchKernelGGL(hashgrid_mlp_kernel, dim3(blocks), dim3(256), 0, stream,
                           pts, table, sidx, W1, W2, out, N, sc);
    } else {
        hipLaunchKernelGGL(hashgrid_mlp_fallback, dim3(blocks), dim3(256), 0, stream,
                           pts, table, W1, W2, out, N, sc);
    }
}